// Round 9
// baseline (26.264 us; speedup 1.0000x reference)
//
#include <hip/hip_runtime.h>

// Fasttext: out[b,t,p] = W @ embed[ids[b,t]] + b, masked t < seq_lengths[b]
// VOCAB=200000, E=300, P=128, B=16, S=2048, BS=32768
//
// R9: eliminate the 2x A-gather duplication (R8 left each embed row read by
// BOTH col-half blocks). Block = 64 tokens x FULL 128 cols, 256 thr/4 waves;
// wave = 16 tokens x 128 cols (acc[8]). Full W staged once per block into
// LDS bf16 fragment-major; tail k-fragment stored COMPACT (only kg=0,1
// halves; kg>=2 lanes have zero A so any finite B is fine) -> 77824 B LDS,
// 2 blocks/CU. Grid 512 (1 tile per block). Gather traffic 39MB -> 20MB.

#define E 300
#define P 128
#define S 2048
#define BS 32768
#define TM 64             // tokens per block tile
#define TAIL_OFF 73728    // 9 full fragments: 9*8*16*64

typedef short bf16x8 __attribute__((ext_vector_type(8)));
typedef short bf16x4 __attribute__((ext_vector_type(4)));
typedef float f32x4 __attribute__((ext_vector_type(4)));

// round-nearest (ties up) f32->bf16: 2 VALU/elem
__device__ inline unsigned short f32_bf16_fast(float f) {
    unsigned int u = __builtin_bit_cast(unsigned int, f);
    return (unsigned short)((u + 0x8000u) >> 16);
}
__device__ inline bf16x8 cvt8(f32x4 a, f32x4 b) {
    bf16x8 r;
    r[0] = (short)f32_bf16_fast(a[0]); r[1] = (short)f32_bf16_fast(a[1]);
    r[2] = (short)f32_bf16_fast(a[2]); r[3] = (short)f32_bf16_fast(a[3]);
    r[4] = (short)f32_bf16_fast(b[0]); r[5] = (short)f32_bf16_fast(b[1]);
    r[6] = (short)f32_bf16_fast(b[2]); r[7] = (short)f32_bf16_fast(b[3]);
    return r;
}
__device__ inline bf16x4 cvt4(f32x4 a) {
    bf16x4 r;
    r[0] = (short)f32_bf16_fast(a[0]); r[1] = (short)f32_bf16_fast(a[1]);
    r[2] = (short)f32_bf16_fast(a[2]); r[3] = (short)f32_bf16_fast(a[3]);
    return r;
}

__global__ __launch_bounds__(256, 2) void ft_main(
    const int* __restrict__ ids, const int* __restrict__ seqlen,
    const float* __restrict__ embed, const float* __restrict__ Wf,
    const float* __restrict__ bias, float* __restrict__ out)
{
    // Full W, bf16, fragment-major:
    //  s<9 : off = ((s*8+ni)*16+fr)*64 + kg*16 + h*8          [0, 73728)
    //  s=9 : off = TAIL_OFF + (ni*16+fr)*32 + (kg&1)*16 + h*8 [73728, 77824)
    __shared__ unsigned char Wl[77824];

    const int tid  = threadIdx.x;
    const int wave = tid >> 6, lane = tid & 63;
    const int fr   = lane & 15, kg = lane >> 4;

    const int tok0 = blockIdx.x * TM;
    const int bi0  = tok0 >> 11;                // batch (64 | 2048)
    const int t0   = tok0 & (S - 1);
    const int sl0  = seqlen[bi0];

    // ---- full-tile mask early-out: zero 64 tokens x 128 cols (32KB) ----
    if (sl0 <= t0) {
        f32x4* o = (f32x4*)(out + (long long)tok0 * P);
        f32x4 z = {0.f, 0.f, 0.f, 0.f};
        #pragma unroll
        for (int i = 0; i < 8; ++i)
            o[tid + i * 256] = z;
        return;
    }

    // ---- A: issue the gather early (19 independent loads per lane) ----
    const int token_a = tok0 + wave * 16 + fr;
    const long long id = ids[token_a];
    const float* __restrict__ rp = embed + id * (long long)E;

    bf16x8 av[10];
    #pragma unroll
    for (int s = 0; s < 9; ++s) {
        const int kb = s * 32 + kg * 8;         // <= 280; ends 287 < 300
        f32x4 f0 = *(const f32x4*)(rp + kb);
        f32x4 f1 = *(const f32x4*)(rp + kb + 4);
        av[s] = cvt8(f0, f1);
    }
    {   // tail: valid k 288..299, exact bounds; kg>=2 lanes -> zero A
        f32x4 z4 = {0.f, 0.f, 0.f, 0.f};
        f32x4 f0 = z4, f1 = z4;
        if (kg == 0)      { f0 = *(const f32x4*)(rp + 288); f1 = *(const f32x4*)(rp + 292); }
        else if (kg == 1) { f0 = *(const f32x4*)(rp + 296); }
        av[9] = cvt8(f0, f1);
    }

    // ---- stage full W (128 rows) -> LDS bf16 fragment-major, compact tail ----
    // flat g4 in [0, 128*80): r = g4/80, c0 = (g4%80)*4 in {0,4,...,316}
    #pragma unroll 8
    for (int i = 0; i < 40; ++i) {
        int g4 = tid + i * 256;
        int r  = g4 / 80;
        int c4 = g4 - r * 80;
        int c0 = c4 * 4;
        if (c0 >= 304) continue;                 // k>=304 never consumed
        f32x4 v = {0.f, 0.f, 0.f, 0.f};
        if (c0 < 300)                            // c0 <= 296 -> reads 296..299, exact
            v = *(const f32x4*)(Wf + (long long)r * E + c0);
        int ni  = r >> 4;
        int fr2 = r & 15;
        int off;
        if (c0 < 288) {
            int s   = c0 >> 5;
            int kgg = (c0 & 31) >> 3;
            int h   = (c0 >> 2) & 1;
            off = (((s * 8 + ni) * 16 + fr2) << 6) + (kgg << 4) + (h << 3);
        } else {
            int kgm = (c0 - 288) >> 3;           // 0 or 1
            int h   = ((c0 - 288) >> 2) & 1;
            off = TAIL_OFF + (((ni * 16 + fr2) << 5) + (kgm << 4) + (h << 3));
        }
        *(bf16x4*)(Wl + off) = cvt4(v);
    }
    __syncthreads();

    // ---- MFMA: 10 k-steps x 8 ni, B from LDS ----
    f32x4 acc[8];
    #pragma unroll
    for (int ni = 0; ni < 8; ++ni) acc[ni] = (f32x4){0.f, 0.f, 0.f, 0.f};

    #pragma unroll
    for (int s = 0; s < 9; ++s) {
        #pragma unroll
        for (int ni = 0; ni < 8; ++ni) {
            bf16x8 bv = *(const bf16x8*)(Wl + ((((s * 8 + ni) * 16 + fr) << 6) + (kg << 4)));
            acc[ni] = __builtin_amdgcn_mfma_f32_16x16x32_bf16(av[s], bv, acc[ni], 0, 0, 0);
        }
    }
    {   // tail step: compact fragment; kg>=2 lanes read kg&1 copy (A there = 0)
        #pragma unroll
        for (int ni = 0; ni < 8; ++ni) {
            bf16x8 bv = *(const bf16x8*)(Wl + TAIL_OFF + (((ni * 16 + fr) << 5) + ((kg & 1) << 4)));
            acc[ni] = __builtin_amdgcn_mfma_f32_16x16x32_bf16(av[9], bv, acc[ni], 0, 0, 0);
        }
    }

    // ---- epilogue: +bias, per-row seq-mask, store ----
    // C/D layout: col(=W row -> P) = lane&15, row(=token) = (lane>>4)*4 + j
    float bs[8];
    #pragma unroll
    for (int ni = 0; ni < 8; ++ni) bs[ni] = bias[ni * 16 + fr];

    #pragma unroll
    for (int j = 0; j < 4; ++j) {
        int orow  = wave * 16 + kg * 4 + j;
        int token = tok0 + orow;
        int t     = token & (S - 1);
        bool valid = (t < sl0);
        #pragma unroll
        for (int ni = 0; ni < 8; ++ni) {
            float v = valid ? (acc[ni][j] + bs[ni]) : 0.0f;
            out[(long long)token * P + ni * 16 + fr] = v;
        }
    }
}

extern "C" void kernel_launch(void* const* d_in, const int* in_sizes, int n_in,
                              void* d_out, int out_size, void* d_ws, size_t ws_size,
                              hipStream_t stream) {
    const int*   ids    = (const int*)d_in[0];
    const int*   sl     = (const int*)d_in[1];
    const float* embed  = (const float*)d_in[2];
    const float* W      = (const float*)d_in[3];
    const float* bias   = (const float*)d_in[4];
    float*       out    = (float*)d_out;

    ft_main<<<BS / TM, 256, 0, stream>>>(ids, sl, embed, W, bias, out);
}